// Round 1
// baseline (689.016 us; speedup 1.0000x reference)
//
#include <hip/hip_runtime.h>
#include <cstdint>
#include <cstddef>

#define NN 50000
#define NE 800000

static __device__ __forceinline__ float lrelu02(float x){ return x > 0.f ? x : 0.2f*x; }

// ---------------- CSR preprocessing ----------------
__global__ void count_kernel(const int* __restrict__ dst, int* __restrict__ cnt, int E){
  int i = blockIdx.x*blockDim.x + threadIdx.x;
  if (i < E) atomicAdd(&cnt[dst[i]], 1);
}

__global__ __launch_bounds__(1024) void scan_kernel(const int* __restrict__ cnt,
      int* __restrict__ rp, int* __restrict__ fillp, float* __restrict__ dinv, int N){
  const int T = 1024;
  int t = threadIdx.x;
  int per = (N + T - 1) / T;           // 49
  int lo = t * per;
  int hi = lo + per; if (hi > N) hi = N;
  int sum = 0;
  for (int i = lo; i < hi; ++i) sum += cnt[i];
  __shared__ int tmp[T];
  tmp[t] = sum;
  __syncthreads();
  for (int off = 1; off < T; off <<= 1){
    int v = (t >= off) ? tmp[t-off] : 0;
    __syncthreads();
    tmp[t] += v;
    __syncthreads();
  }
  int run = tmp[t] - sum;              // exclusive prefix for this thread's chunk
  for (int i = lo; i < hi; ++i){
    int c = cnt[i];
    rp[i] = run; fillp[i] = run;
    dinv[i] = rsqrtf((float)(c + 1));  // deg = in-degree + self-loop, always >= 1
    run += c;
  }
  if (t == T-1) rp[N] = run;           // == E
}

__global__ void fill_kernel(const int* __restrict__ src, const int* __restrict__ dst,
                            int* __restrict__ fillp, int* __restrict__ col, int E){
  int i = blockIdx.x*blockDim.x + threadIdx.x;
  if (i < E){
    int d = dst[i];
    int pos = atomicAdd(&fillp[d], 1);
    col[pos] = src[i];
  }
}

// ---------------- fp32 tiled GEMM: C[MxN] = A[MxK] @ B[KxN] (+bias) ----------------
// BM=64, BN=64, BK=32, 256 threads, 4x4 micro-tile. K%32==0, N%64==0 required.
__global__ __launch_bounds__(256) void gemm_kernel(
    const float* __restrict__ A, const float* __restrict__ B,
    const float* __restrict__ bias, float* __restrict__ C,
    int M, int N, int K)
{
  constexpr int BM=64, BN=64, BK=32;
  __shared__ __align__(16) float As[BK][BM+4];  // +4 keeps 16B alignment for b128 reads
  __shared__ __align__(16) float Bs[BK][BN];
  const int bm = blockIdx.x * BM;
  const int bn = blockIdx.y * BN;
  const int t  = threadIdx.x;
  const int tx = t & 15;
  const int ty = t >> 4;
  float acc[4][4] = {{0.f,0.f,0.f,0.f},{0.f,0.f,0.f,0.f},{0.f,0.f,0.f,0.f},{0.f,0.f,0.f,0.f}};

  for (int k0 = 0; k0 < K; k0 += BK){
    // A tile (store transposed As[k][m])
    {
      const int r = t >> 3;            // 0..31
      const int c = (t & 7) * 4;       // 0,4,...,28
      #pragma unroll
      for (int rr = 0; rr < 2; ++rr){
        const int row = bm + r + rr*32;
        float4 v = make_float4(0.f,0.f,0.f,0.f);
        if (row < M) v = *(const float4*)(A + (size_t)row*K + k0 + c);
        As[c+0][r+rr*32] = v.x;
        As[c+1][r+rr*32] = v.y;
        As[c+2][r+rr*32] = v.z;
        As[c+3][r+rr*32] = v.w;
      }
    }
    // B tile
    {
      const int r = t >> 4;            // 0..15
      const int c = (t & 15) * 4;      // 0..60
      #pragma unroll
      for (int rr = 0; rr < 2; ++rr){
        *(float4*)&Bs[r+rr*16][c] = *(const float4*)(B + (size_t)(k0 + r + rr*16)*N + bn + c);
      }
    }
    __syncthreads();
    #pragma unroll
    for (int k = 0; k < BK; ++k){
      const float4 a = *(const float4*)&As[k][ty*4];
      const float4 b = *(const float4*)&Bs[k][tx*4];
      acc[0][0] += a.x*b.x; acc[0][1] += a.x*b.y; acc[0][2] += a.x*b.z; acc[0][3] += a.x*b.w;
      acc[1][0] += a.y*b.x; acc[1][1] += a.y*b.y; acc[1][2] += a.y*b.z; acc[1][3] += a.y*b.w;
      acc[2][0] += a.z*b.x; acc[2][1] += a.z*b.y; acc[2][2] += a.z*b.z; acc[2][3] += a.z*b.w;
      acc[3][0] += a.w*b.x; acc[3][1] += a.w*b.y; acc[3][2] += a.w*b.z; acc[3][3] += a.w*b.w;
    }
    __syncthreads();
  }

  float bv[4] = {0.f,0.f,0.f,0.f};
  if (bias){
    bv[0] = bias[bn + tx*4 + 0];
    bv[1] = bias[bn + tx*4 + 1];
    bv[2] = bias[bn + tx*4 + 2];
    bv[3] = bias[bn + tx*4 + 3];
  }
  #pragma unroll
  for (int i = 0; i < 4; ++i){
    const int row = bm + ty*4 + i;
    if (row < M){
      float4 v = make_float4(acc[i][0]+bv[0], acc[i][1]+bv[1], acc[i][2]+bv[2], acc[i][3]+bv[3]);
      *(float4*)(C + (size_t)row*N + bn + tx*4) = v;
    }
  }
}

// ---------------- GCN aggregation: out[n] = dinv[n]*(dinv[n]*H[n] + sum dinv[s]*H[s]) + b ----
template<int F>
__global__ __launch_bounds__(256) void gcn_agg_kernel(
    const float* __restrict__ H, const int* __restrict__ rp, const int* __restrict__ col,
    const float* __restrict__ dinv, const float* __restrict__ bias,
    float* __restrict__ out, int N)
{
  const int n    = blockIdx.x * (blockDim.x >> 6) + (threadIdx.x >> 6);
  const int lane = threadIdx.x & 63;
  if (n >= N) return;
  const float dn = dinv[n];
  constexpr int V = F / 64;
  float acc[V];
  if constexpr (V == 2){
    float2 h = *(const float2*)(H + (size_t)n*F + lane*2);
    acc[0] = dn * h.x; acc[1] = dn * h.y;
  } else {
    acc[0] = dn * H[(size_t)n*F + lane];
  }
  const int s0 = rp[n], s1 = rp[n+1];
  for (int i = s0; i < s1; ++i){
    const int s = col[i];
    const float w = dinv[s];
    if constexpr (V == 2){
      float2 h = *(const float2*)(H + (size_t)s*F + lane*2);
      acc[0] += w * h.x; acc[1] += w * h.y;
    } else {
      acc[0] += w * H[(size_t)s*F + lane];
    }
  }
  if constexpr (V == 2){
    float2 bv = *(const float2*)(bias + lane*2);
    *(float2*)(out + (size_t)n*F + lane*2) = make_float2(dn*acc[0] + bv.x, dn*acc[1] + bv.y);
  } else {
    out[(size_t)n*F + lane] = dn*acc[0] + bias[lane];
  }
}

// ---------------- al/ar = HG @ a_src, HG @ a_dst (wave-per-row dot) ----------------
__global__ __launch_bounds__(256) void alar_kernel(const float* __restrict__ HG,
    const float* __restrict__ a_src, const float* __restrict__ a_dst,
    float* __restrict__ al, float* __restrict__ ar, int N)
{
  const int n    = blockIdx.x * (blockDim.x >> 6) + (threadIdx.x >> 6);
  const int lane = threadIdx.x & 63;
  if (n >= N) return;
  float2 h  = *(const float2*)(HG + (size_t)n*128 + lane*2);
  float2 as = *(const float2*)(a_src + lane*2);
  float2 ad = *(const float2*)(a_dst + lane*2);
  float s = h.x*as.x + h.y*as.y;
  float d = h.x*ad.x + h.y*ad.y;
  #pragma unroll
  for (int off = 32; off > 0; off >>= 1){
    s += __shfl_down(s, off, 64);
    d += __shfl_down(d, off, 64);
  }
  if (lane == 0){ al[n] = s; ar[n] = d; }
}

// ---------------- GAT aggregation (online softmax over incident edges + self-loop) ------
// out = relu( (sum_e alpha_e * HG[src_e]) + bg )   with relu fused for the next layer
__global__ __launch_bounds__(256) void gat_agg_kernel(
    const float* __restrict__ HG, const int* __restrict__ rp, const int* __restrict__ col,
    const float* __restrict__ al, const float* __restrict__ ar,
    const float* __restrict__ bias, float* __restrict__ out, int N)
{
  const int n    = blockIdx.x * (blockDim.x >> 6) + (threadIdx.x >> 6);
  const int lane = threadIdx.x & 63;
  if (n >= N) return;
  const float arn = ar[n];
  // self-loop initializes the online-softmax state: p_self = 1
  float m = lrelu02(al[n] + arn);
  float l = 1.f;
  float2 acc = *(const float2*)(HG + (size_t)n*128 + lane*2);
  const int s0 = rp[n], s1 = rp[n+1];
  for (int i = s0; i < s1; ++i){
    const int s = col[i];
    const float e = lrelu02(al[s] + arn);
    const float2 h = *(const float2*)(HG + (size_t)s*128 + lane*2);
    const float mnew = fmaxf(m, e);
    const float sc = __expf(m - mnew);   // 1 when m unchanged
    const float p  = __expf(e - mnew);
    l = l*sc + p;
    acc.x = acc.x*sc + p*h.x;
    acc.y = acc.y*sc + p*h.y;
    m = mnew;
  }
  const float inv = 1.f / l;
  float2 bv = *(const float2*)(bias + lane*2);
  float ox = fmaxf(acc.x*inv + bv.x, 0.f);
  float oy = fmaxf(acc.y*inv + bv.y, 0.f);
  *(float2*)(out + (size_t)n*128 + lane*2) = make_float2(ox, oy);
}

// ---------------- launch ----------------
extern "C" void kernel_launch(void* const* d_in, const int* in_sizes, int n_in,
                              void* d_out, int out_size, void* d_ws, size_t ws_size,
                              hipStream_t stream)
{
  const float* x     = (const float*)d_in[0];
  const int*   ei    = (const int*)d_in[1];
  const float* W1    = (const float*)d_in[2];
  const float* b1    = (const float*)d_in[3];
  const float* Wg    = (const float*)d_in[4];
  const float* a_src = (const float*)d_in[5];
  const float* a_dst = (const float*)d_in[6];
  const float* bg    = (const float*)d_in[7];
  const float* W2    = (const float*)d_in[8];
  const float* b2    = (const float*)d_in[9];
  const float* Wf    = (const float*)d_in[10];
  const float* bf    = (const float*)d_in[11];
  const int N = NN, E = NE;
  const int* src = ei;
  const int* dst = ei + E;

  char* p = (char*)d_ws;
  auto alloc = [&](size_t bytes)->char*{
    char* r = p; p += (bytes + 511) & ~size_t(511); return r;
  };
  int*   cnt   = (int*)  alloc((size_t)N*4);
  int*   rp    = (int*)  alloc((size_t)(N+1)*4);
  int*   fillp = (int*)  alloc((size_t)N*4);
  int*   col   = (int*)  alloc((size_t)E*4);
  float* dinv  = (float*)alloc((size_t)N*4);
  float* al    = (float*)alloc((size_t)N*4);
  float* ar    = (float*)alloc((size_t)N*4);
  float* bufA  = (float*)alloc((size_t)N*128*4);
  float* bufB  = (float*)alloc((size_t)N*128*4);

  hipMemsetAsync(cnt, 0, (size_t)N*4, stream);
  count_kernel<<<(E+255)/256, 256, 0, stream>>>(dst, cnt, E);
  scan_kernel<<<1, 1024, 0, stream>>>(cnt, rp, fillp, dinv, N);
  fill_kernel<<<(E+255)/256, 256, 0, stream>>>(src, dst, fillp, col, E);

  const int gm = (N + 63) / 64;            // 782 row-tiles
  const int ga = (N + 3) / 4;              // 4 waves (nodes) per 256-thread block

  // GEMM1: x[N,192] @ W1[192,128] -> bufA
  gemm_kernel<<<dim3(gm, 2), 256, 0, stream>>>(x, W1, nullptr, bufA, N, 128, 192);
  // AGG1 (GCN): bufA -> bufB (+b1)
  gcn_agg_kernel<128><<<ga, 256, 0, stream>>>(bufA, rp, col, dinv, b1, bufB, N);
  // GEMM2: bufB[N,128] @ Wg[128,128] -> bufA (HG)
  gemm_kernel<<<dim3(gm, 2), 256, 0, stream>>>(bufB, Wg, nullptr, bufA, N, 128, 128);
  // al/ar from HG
  alar_kernel<<<ga, 256, 0, stream>>>(bufA, a_src, a_dst, al, ar, N);
  // GAT: bufA -> bufB (+bg, relu fused)
  gat_agg_kernel<<<ga, 256, 0, stream>>>(bufA, rp, col, al, ar, bg, bufB, N);
  // GEMM3: bufB[N,128] @ W2[128,64] -> bufA
  gemm_kernel<<<dim3(gm, 1), 256, 0, stream>>>(bufB, W2, nullptr, bufA, N, 64, 128);
  // AGG2 (GCN): bufA -> bufB (+b2), F=64
  gcn_agg_kernel<64><<<ga, 256, 0, stream>>>(bufA, rp, col, dinv, b2, bufB, N);
  // GEMM4: bufB[N,64] @ Wf[64,192] + bf -> d_out
  gemm_kernel<<<dim3(gm, 3), 256, 0, stream>>>(bufB, Wf, bf, (float*)d_out, N, 192, 64);
}

// Round 2
// 570.586 us; speedup vs baseline: 1.2076x; 1.2076x over previous
//
#include <hip/hip_runtime.h>
#include <cstdint>
#include <cstddef>

#define NN 50000
#define NE 800000

static __device__ __forceinline__ float lrelu02(float x){ return x > 0.f ? x : 0.2f*x; }

// ---------------- CSR preprocessing ----------------
__global__ void count_kernel(const int* __restrict__ dst, int* __restrict__ cnt, int E){
  int i = blockIdx.x*blockDim.x + threadIdx.x;
  if (i < E) atomicAdd(&cnt[dst[i]], 1);
}

// Phase 1: per-1024-chunk inclusive scan + block sums
__global__ __launch_bounds__(1024) void scan1_kernel(const int* __restrict__ cnt,
      int* __restrict__ incl, int* __restrict__ bsum, int N){
  __shared__ int tmp[1024];
  const int t = threadIdx.x;
  const int i = blockIdx.x*1024 + t;
  int v = (i < N) ? cnt[i] : 0;
  tmp[t] = v;
  __syncthreads();
  #pragma unroll
  for (int off = 1; off < 1024; off <<= 1){
    int u = (t >= off) ? tmp[t-off] : 0;
    __syncthreads();
    tmp[t] += u;
    __syncthreads();
  }
  if (i < N) incl[i] = tmp[t];
  if (t == 1023) bsum[blockIdx.x] = tmp[t];
}

// Phase 2: exclusive scan of the (<=64) block sums with one wave
__global__ void scan2_kernel(int* __restrict__ bsum, int NB){
  const int t = threadIdx.x;  // 64 threads
  int own = (t < NB) ? bsum[t] : 0;
  int v = own;
  #pragma unroll
  for (int off = 1; off < 64; off <<= 1){
    int u = __shfl_up(v, off, 64);
    if (t >= off) v += u;
  }
  if (t < NB) bsum[t] = v - own;   // exclusive block offset
}

// Phase 3: global exclusive prefix -> rp/fillp, dinv
__global__ void scan3_kernel(const int* __restrict__ cnt, const int* __restrict__ incl,
      const int* __restrict__ bsum, int* __restrict__ rp, int* __restrict__ fillp,
      float* __restrict__ dinv, int N){
  const int i = blockIdx.x*blockDim.x + threadIdx.x;
  if (i >= N) return;
  const int c = cnt[i];
  const int e = bsum[i >> 10] + incl[i] - c;   // global exclusive prefix
  rp[i] = e; fillp[i] = e;
  dinv[i] = rsqrtf((float)(c + 1));            // deg = in-degree + self-loop
  if (i == N-1) rp[N] = e + c;                 // == E
}

__global__ void fill_kernel(const int* __restrict__ src, const int* __restrict__ dst,
                            int* __restrict__ fillp, int* __restrict__ col, int E){
  int i = blockIdx.x*blockDim.x + threadIdx.x;
  if (i < E){
    int d = dst[i];
    int pos = atomicAdd(&fillp[d], 1);
    col[pos] = src[i];
  }
}

// ---------------- fp32 tiled GEMM: C[MxN] = A[MxK] @ B[KxN] (+bias) ----------------
// BM=64, BN=64, BK=32, 256 threads, 4x4 micro-tile. K%32==0, N%64==0 required.
__global__ __launch_bounds__(256) void gemm_kernel(
    const float* __restrict__ A, const float* __restrict__ B,
    const float* __restrict__ bias, float* __restrict__ C,
    int M, int N, int K)
{
  constexpr int BM=64, BN=64, BK=32;
  __shared__ __align__(16) float As[BK][BM+4];  // +4 keeps 16B alignment for b128 reads
  __shared__ __align__(16) float Bs[BK][BN];
  const int bm = blockIdx.x * BM;
  const int bn = blockIdx.y * BN;
  const int t  = threadIdx.x;
  const int tx = t & 15;
  const int ty = t >> 4;
  float acc[4][4] = {{0.f,0.f,0.f,0.f},{0.f,0.f,0.f,0.f},{0.f,0.f,0.f,0.f},{0.f,0.f,0.f,0.f}};

  for (int k0 = 0; k0 < K; k0 += BK){
    // A tile (store transposed As[k][m])
    {
      const int r = t >> 3;            // 0..31
      const int c = (t & 7) * 4;       // 0,4,...,28
      #pragma unroll
      for (int rr = 0; rr < 2; ++rr){
        const int row = bm + r + rr*32;
        float4 v = make_float4(0.f,0.f,0.f,0.f);
        if (row < M) v = *(const float4*)(A + (size_t)row*K + k0 + c);
        As[c+0][r+rr*32] = v.x;
        As[c+1][r+rr*32] = v.y;
        As[c+2][r+rr*32] = v.z;
        As[c+3][r+rr*32] = v.w;
      }
    }
    // B tile
    {
      const int r = t >> 4;            // 0..15
      const int c = (t & 15) * 4;      // 0..60
      #pragma unroll
      for (int rr = 0; rr < 2; ++rr){
        *(float4*)&Bs[r+rr*16][c] = *(const float4*)(B + (size_t)(k0 + r + rr*16)*N + bn + c);
      }
    }
    __syncthreads();
    #pragma unroll
    for (int k = 0; k < BK; ++k){
      const float4 a = *(const float4*)&As[k][ty*4];
      const float4 b = *(const float4*)&Bs[k][tx*4];
      acc[0][0] += a.x*b.x; acc[0][1] += a.x*b.y; acc[0][2] += a.x*b.z; acc[0][3] += a.x*b.w;
      acc[1][0] += a.y*b.x; acc[1][1] += a.y*b.y; acc[1][2] += a.y*b.z; acc[1][3] += a.y*b.w;
      acc[2][0] += a.z*b.x; acc[2][1] += a.z*b.y; acc[2][2] += a.z*b.z; acc[2][3] += a.z*b.w;
      acc[3][0] += a.w*b.x; acc[3][1] += a.w*b.y; acc[3][2] += a.w*b.z; acc[3][3] += a.w*b.w;
    }
    __syncthreads();
  }

  float bv[4] = {0.f,0.f,0.f,0.f};
  if (bias){
    bv[0] = bias[bn + tx*4 + 0];
    bv[1] = bias[bn + tx*4 + 1];
    bv[2] = bias[bn + tx*4 + 2];
    bv[3] = bias[bn + tx*4 + 3];
  }
  #pragma unroll
  for (int i = 0; i < 4; ++i){
    const int row = bm + ty*4 + i;
    if (row < M){
      float4 v = make_float4(acc[i][0]+bv[0], acc[i][1]+bv[1], acc[i][2]+bv[2], acc[i][3]+bv[3]);
      *(float4*)(C + (size_t)row*N + bn + tx*4) = v;
    }
  }
}

// ---------------- GCN aggregation: out[n] = dinv[n]*(dinv[n]*H[n] + sum dinv[s]*H[s]) + b ----
template<int F>
__global__ __launch_bounds__(256) void gcn_agg_kernel(
    const float* __restrict__ H, const int* __restrict__ rp, const int* __restrict__ col,
    const float* __restrict__ dinv, const float* __restrict__ bias,
    float* __restrict__ out, int N)
{
  const int n    = blockIdx.x * (blockDim.x >> 6) + (threadIdx.x >> 6);
  const int lane = threadIdx.x & 63;
  if (n >= N) return;
  const float dn = dinv[n];
  constexpr int V = F / 64;
  float acc[V];
  if constexpr (V == 2){
    float2 h = *(const float2*)(H + (size_t)n*F + lane*2);
    acc[0] = dn * h.x; acc[1] = dn * h.y;
  } else {
    acc[0] = dn * H[(size_t)n*F + lane];
  }
  const int s0 = rp[n], s1 = rp[n+1];
  for (int i = s0; i < s1; ++i){
    const int s = col[i];
    const float w = dinv[s];
    if constexpr (V == 2){
      float2 h = *(const float2*)(H + (size_t)s*F + lane*2);
      acc[0] += w * h.x; acc[1] += w * h.y;
    } else {
      acc[0] += w * H[(size_t)s*F + lane];
    }
  }
  if constexpr (V == 2){
    float2 bv = *(const float2*)(bias + lane*2);
    *(float2*)(out + (size_t)n*F + lane*2) = make_float2(dn*acc[0] + bv.x, dn*acc[1] + bv.y);
  } else {
    out[(size_t)n*F + lane] = dn*acc[0] + bias[lane];
  }
}

// ---------------- al/ar = HG @ a_src, HG @ a_dst (wave-per-row dot) ----------------
__global__ __launch_bounds__(256) void alar_kernel(const float* __restrict__ HG,
    const float* __restrict__ a_src, const float* __restrict__ a_dst,
    float* __restrict__ al, float* __restrict__ ar, int N)
{
  const int n    = blockIdx.x * (blockDim.x >> 6) + (threadIdx.x >> 6);
  const int lane = threadIdx.x & 63;
  if (n >= N) return;
  float2 h  = *(const float2*)(HG + (size_t)n*128 + lane*2);
  float2 as = *(const float2*)(a_src + lane*2);
  float2 ad = *(const float2*)(a_dst + lane*2);
  float s = h.x*as.x + h.y*as.y;
  float d = h.x*ad.x + h.y*ad.y;
  #pragma unroll
  for (int off = 32; off > 0; off >>= 1){
    s += __shfl_down(s, off, 64);
    d += __shfl_down(d, off, 64);
  }
  if (lane == 0){ al[n] = s; ar[n] = d; }
}

// ---------------- GAT aggregation (online softmax over incident edges + self-loop) ------
// out = relu( (sum_e alpha_e * HG[src_e]) + bg )   with relu fused for the next layer
__global__ __launch_bounds__(256) void gat_agg_kernel(
    const float* __restrict__ HG, const int* __restrict__ rp, const int* __restrict__ col,
    const float* __restrict__ al, const float* __restrict__ ar,
    const float* __restrict__ bias, float* __restrict__ out, int N)
{
  const int n    = blockIdx.x * (blockDim.x >> 6) + (threadIdx.x >> 6);
  const int lane = threadIdx.x & 63;
  if (n >= N) return;
  const float arn = ar[n];
  // self-loop initializes the online-softmax state: p_self = 1
  float m = lrelu02(al[n] + arn);
  float l = 1.f;
  float2 acc = *(const float2*)(HG + (size_t)n*128 + lane*2);
  const int s0 = rp[n], s1 = rp[n+1];
  for (int i = s0; i < s1; ++i){
    const int s = col[i];
    const float e = lrelu02(al[s] + arn);
    const float2 h = *(const float2*)(HG + (size_t)s*128 + lane*2);
    const float mnew = fmaxf(m, e);
    const float sc = __expf(m - mnew);   // 1 when m unchanged
    const float p  = __expf(e - mnew);
    l = l*sc + p;
    acc.x = acc.x*sc + p*h.x;
    acc.y = acc.y*sc + p*h.y;
    m = mnew;
  }
  const float inv = 1.f / l;
  float2 bv = *(const float2*)(bias + lane*2);
  float ox = fmaxf(acc.x*inv + bv.x, 0.f);
  float oy = fmaxf(acc.y*inv + bv.y, 0.f);
  *(float2*)(out + (size_t)n*128 + lane*2) = make_float2(ox, oy);
}

// ---------------- launch ----------------
extern "C" void kernel_launch(void* const* d_in, const int* in_sizes, int n_in,
                              void* d_out, int out_size, void* d_ws, size_t ws_size,
                              hipStream_t stream)
{
  const float* x     = (const float*)d_in[0];
  const int*   ei    = (const int*)d_in[1];
  const float* W1    = (const float*)d_in[2];
  const float* b1    = (const float*)d_in[3];
  const float* Wg    = (const float*)d_in[4];
  const float* a_src = (const float*)d_in[5];
  const float* a_dst = (const float*)d_in[6];
  const float* bg    = (const float*)d_in[7];
  const float* W2    = (const float*)d_in[8];
  const float* b2    = (const float*)d_in[9];
  const float* Wf    = (const float*)d_in[10];
  const float* bf    = (const float*)d_in[11];
  const int N = NN, E = NE;
  const int* src = ei;
  const int* dst = ei + E;

  char* p = (char*)d_ws;
  auto alloc = [&](size_t bytes)->char*{
    char* r = p; p += (bytes + 511) & ~size_t(511); return r;
  };
  int*   cnt   = (int*)  alloc((size_t)N*4);
  int*   incl  = (int*)  alloc((size_t)N*4);
  int*   bsum  = (int*)  alloc(64*4);
  int*   rp    = (int*)  alloc((size_t)(N+1)*4);
  int*   fillp = (int*)  alloc((size_t)N*4);
  int*   col   = (int*)  alloc((size_t)E*4);
  float* dinv  = (float*)alloc((size_t)N*4);
  float* al    = (float*)alloc((size_t)N*4);
  float* ar    = (float*)alloc((size_t)N*4);
  float* bufA  = (float*)alloc((size_t)N*128*4);
  float* bufB  = (float*)alloc((size_t)N*128*4);

  const int NB = (N + 1023) / 1024;        // 49

  hipMemsetAsync(cnt, 0, (size_t)N*4, stream);
  count_kernel<<<(E+255)/256, 256, 0, stream>>>(dst, cnt, E);
  scan1_kernel<<<NB, 1024, 0, stream>>>(cnt, incl, bsum, N);
  scan2_kernel<<<1, 64, 0, stream>>>(bsum, NB);
  scan3_kernel<<<(N+255)/256, 256, 0, stream>>>(cnt, incl, bsum, rp, fillp, dinv, N);
  fill_kernel<<<(E+255)/256, 256, 0, stream>>>(src, dst, fillp, col, E);

  const int gm = (N + 63) / 64;            // 782 row-tiles
  const int ga = (N + 3) / 4;              // 4 waves (nodes) per 256-thread block

  // GEMM1: x[N,192] @ W1[192,128] -> bufA
  gemm_kernel<<<dim3(gm, 2), 256, 0, stream>>>(x, W1, nullptr, bufA, N, 128, 192);
  // AGG1 (GCN): bufA -> bufB (+b1)
  gcn_agg_kernel<128><<<ga, 256, 0, stream>>>(bufA, rp, col, dinv, b1, bufB, N);
  // GEMM2: bufB[N,128] @ Wg[128,128] -> bufA (HG)
  gemm_kernel<<<dim3(gm, 2), 256, 0, stream>>>(bufB, Wg, nullptr, bufA, N, 128, 128);
  // al/ar from HG
  alar_kernel<<<ga, 256, 0, stream>>>(bufA, a_src, a_dst, al, ar, N);
  // GAT: bufA -> bufB (+bg, relu fused)
  gat_agg_kernel<<<ga, 256, 0, stream>>>(bufA, rp, col, al, ar, bg, bufB, N);
  // GEMM3: bufB[N,128] @ W2[128,64] -> bufA
  gemm_kernel<<<dim3(gm, 1), 256, 0, stream>>>(bufB, W2, nullptr, bufA, N, 64, 128);
  // AGG2 (GCN): bufA -> bufB (+b2), F=64
  gcn_agg_kernel<64><<<ga, 256, 0, stream>>>(bufA, rp, col, dinv, b2, bufB, N);
  // GEMM4: bufB[N,64] @ Wf[64,192] + bf -> d_out
  gemm_kernel<<<dim3(gm, 3), 256, 0, stream>>>(bufB, Wf, bf, (float*)d_out, N, 192, 64);
}

// Round 3
// 512.437 us; speedup vs baseline: 1.3446x; 1.1135x over previous
//
#include <hip/hip_runtime.h>
#include <cstdint>
#include <cstddef>

#define NN 50000
#define NE 800000

static __device__ __forceinline__ float lrelu02(float x){ return x > 0.f ? x : 0.2f*x; }

// ---------------- CSR preprocessing ----------------
__global__ void count_kernel(const int* __restrict__ dst, int* __restrict__ cnt, int E){
  int i = blockIdx.x*blockDim.x + threadIdx.x;
  if (i < E) atomicAdd(&cnt[dst[i]], 1);
}

// Phase 1: per-1024-chunk inclusive scan + block sums
__global__ __launch_bounds__(1024) void scan1_kernel(const int* __restrict__ cnt,
      int* __restrict__ incl, int* __restrict__ bsum, int N){
  __shared__ int tmp[1024];
  const int t = threadIdx.x;
  const int i = blockIdx.x*1024 + t;
  int v = (i < N) ? cnt[i] : 0;
  tmp[t] = v;
  __syncthreads();
  #pragma unroll
  for (int off = 1; off < 1024; off <<= 1){
    int u = (t >= off) ? tmp[t-off] : 0;
    __syncthreads();
    tmp[t] += u;
    __syncthreads();
  }
  if (i < N) incl[i] = tmp[t];
  if (t == 1023) bsum[blockIdx.x] = tmp[t];
}

// Phase 2: exclusive scan of the (<=64) block sums with one wave
__global__ void scan2_kernel(int* __restrict__ bsum, int NB){
  const int t = threadIdx.x;  // 64 threads
  int own = (t < NB) ? bsum[t] : 0;
  int v = own;
  #pragma unroll
  for (int off = 1; off < 64; off <<= 1){
    int u = __shfl_up(v, off, 64);
    if (t >= off) v += u;
  }
  if (t < NB) bsum[t] = v - own;   // exclusive block offset
}

// Phase 3: global exclusive prefix -> rp/fillp, dinv
__global__ void scan3_kernel(const int* __restrict__ cnt, const int* __restrict__ incl,
      const int* __restrict__ bsum, int* __restrict__ rp, int* __restrict__ fillp,
      float* __restrict__ dinv, int N){
  const int i = blockIdx.x*blockDim.x + threadIdx.x;
  if (i >= N) return;
  const int c = cnt[i];
  const int e = bsum[i >> 10] + incl[i] - c;   // global exclusive prefix
  rp[i] = e; fillp[i] = e;
  dinv[i] = rsqrtf((float)(c + 1));            // deg = in-degree + self-loop
  if (i == N-1) rp[N] = e + c;                 // == E
}

__global__ void fill_kernel(const int* __restrict__ src, const int* __restrict__ dst,
                            int* __restrict__ fillp, int* __restrict__ col, int E){
  int i = blockIdx.x*blockDim.x + threadIdx.x;
  if (i < E){
    int d = dst[i];
    int pos = atomicAdd(&fillp[d], 1);
    col[pos] = src[i];
  }
}

// ---------------- fp32 tiled GEMM: C[MxN] = A[MxK] @ B[KxN] (+bias) ----------------
__global__ __launch_bounds__(256) void gemm_kernel(
    const float* __restrict__ A, const float* __restrict__ B,
    const float* __restrict__ bias, float* __restrict__ C,
    int M, int N, int K)
{
  constexpr int BM=64, BN=64, BK=32;
  __shared__ __align__(16) float As[BK][BM+4];
  __shared__ __align__(16) float Bs[BK][BN];
  const int bm = blockIdx.x * BM;
  const int bn = blockIdx.y * BN;
  const int t  = threadIdx.x;
  const int tx = t & 15;
  const int ty = t >> 4;
  float acc[4][4] = {{0.f,0.f,0.f,0.f},{0.f,0.f,0.f,0.f},{0.f,0.f,0.f,0.f},{0.f,0.f,0.f,0.f}};

  for (int k0 = 0; k0 < K; k0 += BK){
    {
      const int r = t >> 3;
      const int c = (t & 7) * 4;
      #pragma unroll
      for (int rr = 0; rr < 2; ++rr){
        const int row = bm + r + rr*32;
        float4 v = make_float4(0.f,0.f,0.f,0.f);
        if (row < M) v = *(const float4*)(A + (size_t)row*K + k0 + c);
        As[c+0][r+rr*32] = v.x;
        As[c+1][r+rr*32] = v.y;
        As[c+2][r+rr*32] = v.z;
        As[c+3][r+rr*32] = v.w;
      }
    }
    {
      const int r = t >> 4;
      const int c = (t & 15) * 4;
      #pragma unroll
      for (int rr = 0; rr < 2; ++rr){
        *(float4*)&Bs[r+rr*16][c] = *(const float4*)(B + (size_t)(k0 + r + rr*16)*N + bn + c);
      }
    }
    __syncthreads();
    #pragma unroll
    for (int k = 0; k < BK; ++k){
      const float4 a = *(const float4*)&As[k][ty*4];
      const float4 b = *(const float4*)&Bs[k][tx*4];
      acc[0][0] += a.x*b.x; acc[0][1] += a.x*b.y; acc[0][2] += a.x*b.z; acc[0][3] += a.x*b.w;
      acc[1][0] += a.y*b.x; acc[1][1] += a.y*b.y; acc[1][2] += a.y*b.z; acc[1][3] += a.y*b.w;
      acc[2][0] += a.z*b.x; acc[2][1] += a.z*b.y; acc[2][2] += a.z*b.z; acc[2][3] += a.z*b.w;
      acc[3][0] += a.w*b.x; acc[3][1] += a.w*b.y; acc[3][2] += a.w*b.z; acc[3][3] += a.w*b.w;
    }
    __syncthreads();
  }

  float bv[4] = {0.f,0.f,0.f,0.f};
  if (bias){
    bv[0] = bias[bn + tx*4 + 0];
    bv[1] = bias[bn + tx*4 + 1];
    bv[2] = bias[bn + tx*4 + 2];
    bv[3] = bias[bn + tx*4 + 3];
  }
  #pragma unroll
  for (int i = 0; i < 4; ++i){
    const int row = bm + ty*4 + i;
    if (row < M){
      float4 v = make_float4(acc[i][0]+bv[0], acc[i][1]+bv[1], acc[i][2]+bv[2], acc[i][3]+bv[3]);
      *(float4*)(C + (size_t)row*N + bn + tx*4) = v;
    }
  }
}

// ---------------- GCN aggregation, chunked parallel gather ----------------
// out[n] = dinv[n]*(dinv[n]*H[n] + sum_s dinv[s]*H[s]) + b
template<int F>
__global__ __launch_bounds__(256) void gcn_agg_kernel(
    const float* __restrict__ H, const int* __restrict__ rp, const int* __restrict__ col,
    const float* __restrict__ dinv, const float* __restrict__ bias,
    float* __restrict__ out, int N)
{
  const int n    = blockIdx.x * (blockDim.x >> 6) + (threadIdx.x >> 6);
  const int lane = threadIdx.x & 63;
  if (n >= N) return;
  const float dn = dinv[n];
  constexpr int V = F / 64;
  float acc[V];
  if constexpr (V == 2){
    float2 h = *(const float2*)(H + (size_t)n*F + lane*2);
    acc[0] = dn * h.x; acc[1] = dn * h.y;
  } else {
    acc[0] = dn * H[(size_t)n*F + lane];
  }
  const int s0 = rp[n], s1 = rp[n+1];
  for (int c0 = s0; c0 < s1; c0 += 64){
    const int nc = min(64, s1 - c0);
    // one coalesced load: 64 indices; one gather: 64 weights
    int   sl = (lane < nc) ? col[c0 + lane] : 0;
    float wl = (lane < nc) ? dinv[sl] : 0.f;
    #pragma unroll 4
    for (int j = 0; j < nc; ++j){
      const int   s = __shfl(sl, j, 64);
      const float w = __shfl(wl, j, 64);
      if constexpr (V == 2){
        float2 h = *(const float2*)(H + (size_t)s*F + lane*2);
        acc[0] += w * h.x; acc[1] += w * h.y;
      } else {
        acc[0] += w * H[(size_t)s*F + lane];
      }
    }
  }
  if constexpr (V == 2){
    float2 bv = *(const float2*)(bias + lane*2);
    *(float2*)(out + (size_t)n*F + lane*2) = make_float2(dn*acc[0] + bv.x, dn*acc[1] + bv.y);
  } else {
    out[(size_t)n*F + lane] = dn*acc[0] + bias[lane];
  }
}

// ---------------- al/ar = HG @ a_src, HG @ a_dst (wave-per-row dot) ----------------
__global__ __launch_bounds__(256) void alar_kernel(const float* __restrict__ HG,
    const float* __restrict__ a_src, const float* __restrict__ a_dst,
    float* __restrict__ al, float* __restrict__ ar, int N)
{
  const int n    = blockIdx.x * (blockDim.x >> 6) + (threadIdx.x >> 6);
  const int lane = threadIdx.x & 63;
  if (n >= N) return;
  float2 h  = *(const float2*)(HG + (size_t)n*128 + lane*2);
  float2 as = *(const float2*)(a_src + lane*2);
  float2 ad = *(const float2*)(a_dst + lane*2);
  float s = h.x*as.x + h.y*as.y;
  float d = h.x*ad.x + h.y*ad.y;
  #pragma unroll
  for (int off = 32; off > 0; off >>= 1){
    s += __shfl_down(s, off, 64);
    d += __shfl_down(d, off, 64);
  }
  if (lane == 0){ al[n] = s; ar[n] = d; }
}

// ---------------- GAT aggregation, chunked softmax + parallel gather ----------------
// out = relu( (sum_e alpha_e * HG[src_e]) + bg ), softmax over incident edges + self-loop
__global__ __launch_bounds__(256) void gat_agg_kernel(
    const float* __restrict__ HG, const int* __restrict__ rp, const int* __restrict__ col,
    const float* __restrict__ al, const float* __restrict__ ar,
    const float* __restrict__ bias, float* __restrict__ out, int N)
{
  const int n    = blockIdx.x * (blockDim.x >> 6) + (threadIdx.x >> 6);
  const int lane = threadIdx.x & 63;
  if (n >= N) return;
  const float arn = ar[n];
  // self-loop initializes state: p_self = exp(e_self - m) with m = e_self -> 1
  float m = lrelu02(al[n] + arn);
  float l = 1.f;
  float2 acc = *(const float2*)(HG + (size_t)n*128 + lane*2);
  const int s0 = rp[n], s1 = rp[n+1];
  for (int c0 = s0; c0 < s1; c0 += 64){
    const int nc = min(64, s1 - c0);
    // batched gathers: 64 indices in one load, 64 scores in one gather
    int   sl = (lane < nc) ? col[c0 + lane] : 0;
    float el = (lane < nc) ? lrelu02(al[sl] + arn) : -3.4e38f;
    // chunk max (parallel)
    float cm = el;
    #pragma unroll
    for (int off = 32; off > 0; off >>= 1) cm = fmaxf(cm, __shfl_xor(cm, off, 64));
    const float mnew = fmaxf(m, cm);
    const float sc = __expf(m - mnew);
    // all p in parallel
    float pl = (lane < nc) ? __expf(el - mnew) : 0.f;
    float ps = pl;
    #pragma unroll
    for (int off = 32; off > 0; off >>= 1) ps += __shfl_xor(ps, off, 64);
    l = l*sc + ps;
    acc.x *= sc; acc.y *= sc;
    // independent row accumulates; s/p broadcast from registers
    #pragma unroll 4
    for (int j = 0; j < nc; ++j){
      const int   s = __shfl(sl, j, 64);
      const float p = __shfl(pl, j, 64);
      const float2 h = *(const float2*)(HG + (size_t)s*128 + lane*2);
      acc.x += p*h.x; acc.y += p*h.y;
    }
    m = mnew;
  }
  const float inv = 1.f / l;
  float2 bv = *(const float2*)(bias + lane*2);
  float ox = fmaxf(acc.x*inv + bv.x, 0.f);
  float oy = fmaxf(acc.y*inv + bv.y, 0.f);
  *(float2*)(out + (size_t)n*128 + lane*2) = make_float2(ox, oy);
}

// ---------------- launch ----------------
extern "C" void kernel_launch(void* const* d_in, const int* in_sizes, int n_in,
                              void* d_out, int out_size, void* d_ws, size_t ws_size,
                              hipStream_t stream)
{
  const float* x     = (const float*)d_in[0];
  const int*   ei    = (const int*)d_in[1];
  const float* W1    = (const float*)d_in[2];
  const float* b1    = (const float*)d_in[3];
  const float* Wg    = (const float*)d_in[4];
  const float* a_src = (const float*)d_in[5];
  const float* a_dst = (const float*)d_in[6];
  const float* bg    = (const float*)d_in[7];
  const float* W2    = (const float*)d_in[8];
  const float* b2    = (const float*)d_in[9];
  const float* Wf    = (const float*)d_in[10];
  const float* bf    = (const float*)d_in[11];
  const int N = NN, E = NE;
  const int* src = ei;
  const int* dst = ei + E;

  char* p = (char*)d_ws;
  auto alloc = [&](size_t bytes)->char*{
    char* r = p; p += (bytes + 511) & ~size_t(511); return r;
  };
  int*   cnt   = (int*)  alloc((size_t)N*4);
  int*   incl  = (int*)  alloc((size_t)N*4);
  int*   bsum  = (int*)  alloc(64*4);
  int*   rp    = (int*)  alloc((size_t)(N+1)*4);
  int*   fillp = (int*)  alloc((size_t)N*4);
  int*   col   = (int*)  alloc((size_t)E*4);
  float* dinv  = (float*)alloc((size_t)N*4);
  float* al    = (float*)alloc((size_t)N*4);
  float* ar    = (float*)alloc((size_t)N*4);
  float* bufA  = (float*)alloc((size_t)N*128*4);
  float* bufB  = (float*)alloc((size_t)N*128*4);

  const int NB = (N + 1023) / 1024;

  hipMemsetAsync(cnt, 0, (size_t)N*4, stream);
  count_kernel<<<(E+255)/256, 256, 0, stream>>>(dst, cnt, E);
  scan1_kernel<<<NB, 1024, 0, stream>>>(cnt, incl, bsum, N);
  scan2_kernel<<<1, 64, 0, stream>>>(bsum, NB);
  scan3_kernel<<<(N+255)/256, 256, 0, stream>>>(cnt, incl, bsum, rp, fillp, dinv, N);
  fill_kernel<<<(E+255)/256, 256, 0, stream>>>(src, dst, fillp, col, E);

  const int gm = (N + 63) / 64;
  const int ga = (N + 3) / 4;

  gemm_kernel<<<dim3(gm, 2), 256, 0, stream>>>(x, W1, nullptr, bufA, N, 128, 192);
  gcn_agg_kernel<128><<<ga, 256, 0, stream>>>(bufA, rp, col, dinv, b1, bufB, N);
  gemm_kernel<<<dim3(gm, 2), 256, 0, stream>>>(bufB, Wg, nullptr, bufA, N, 128, 128);
  alar_kernel<<<ga, 256, 0, stream>>>(bufA, a_src, a_dst, al, ar, N);
  gat_agg_kernel<<<ga, 256, 0, stream>>>(bufA, rp, col, al, ar, bg, bufB, N);
  gemm_kernel<<<dim3(gm, 1), 256, 0, stream>>>(bufB, W2, nullptr, bufA, N, 64, 128);
  gcn_agg_kernel<64><<<ga, 256, 0, stream>>>(bufA, rp, col, dinv, b2, bufB, N);
  gemm_kernel<<<dim3(gm, 3), 256, 0, stream>>>(bufB, Wf, bf, (float*)d_out, N, 192, 64);
}